// Round 2
// baseline (537.801 us; speedup 1.0000x reference)
//
#include <hip/hip_runtime.h>
#include <math.h>

#define PN 22536
#define BN 32
#define MN 16
#define CN 81
#define NBX 177        // loss blocks per image; 177*4 waves = 708 priors/iter
#define LOSS_ITERS 32  // 708*32 = 22656 >= 22536

// ---------------------------------------------------------------------------
// Kernel 1: per-object best-prior argmax (prior_for_each_object).
// Packed key (iou_bits<<32 | ~p): max => first-occurrence argmax over p.
// LDS pre-reduction => only 16 global atomics per block.
// ---------------------------------------------------------------------------
__global__ __launch_bounds__(256)
void pfo_kernel(const float* __restrict__ boxes,    // (B,M,4) xyxy
                const float* __restrict__ priors,   // (P,4) cxcy
                unsigned long long* __restrict__ pfo_key) // (B,M)
{
    const int b = blockIdx.y;
    const int p = blockIdx.x * 256 + threadIdx.x;

    __shared__ float4 sbox[MN];
    __shared__ float  sarea[MN];
    __shared__ unsigned long long skey[MN];
    if (threadIdx.x < MN) {
        float4 bx = reinterpret_cast<const float4*>(boxes)[b * MN + threadIdx.x];
        sbox[threadIdx.x]  = bx;
        sarea[threadIdx.x] = (bx.z - bx.x) * (bx.w - bx.y);
        skey[threadIdx.x]  = 0ull;
    }
    __syncthreads();

    float x0 = 0.f, y0 = 0.f, x1 = 0.f, y1 = 0.f, ab = 0.f;
    const bool valid = (p < PN);
    if (valid) {
        float4 pc = reinterpret_cast<const float4*>(priors)[p];
        float hw = pc.z / 2.0f, hh = pc.w / 2.0f;
        x0 = pc.x - hw; y0 = pc.y - hh;
        x1 = pc.x + hw; y1 = pc.y + hh;
        ab = (x1 - x0) * (y1 - y0);
    }

    const int lane = threadIdx.x & 63;
    #pragma unroll
    for (int m = 0; m < MN; ++m) {
        unsigned long long key = 0ull;
        if (valid) {
            float4 bx = sbox[m];
            float lx = fmaxf(bx.x, x0), ly = fmaxf(bx.y, y0);
            float rx = fminf(bx.z, x1), ry = fminf(bx.w, y1);
            float inter = fmaxf(rx - lx, 0.0f) * fmaxf(ry - ly, 0.0f);
            float iou = inter / (sarea[m] + ab - inter);
            key = ((unsigned long long)__float_as_uint(iou) << 32) |
                  (unsigned long long)(~(unsigned int)p);
        }
        #pragma unroll
        for (int off = 32; off >= 1; off >>= 1) {
            unsigned long long o = __shfl_down(key, (unsigned)off, 64);
            if (o > key) key = o;
        }
        if (lane == 0) atomicMax(&skey[m], key);
    }
    __syncthreads();
    if (threadIdx.x < MN)
        atomicMax(&pfo_key[b * MN + threadIdx.x], skey[threadIdx.x]);
}

// ---------------------------------------------------------------------------
// Kernel 2: fused match-recompute + focal + DIoU. ONE WAVE PER PRIOR.
// Lanes 0..15 recompute the 16 IoUs (cheap); score row (81 floats) read with
// two coalesced loads; butterfly reductions for max / sum-exp.
// ---------------------------------------------------------------------------
__global__ __launch_bounds__(256)
void loss_kernel(const float* __restrict__ plocs,   // (B,P,4)
                 const float* __restrict__ scores,  // (B,P,C)
                 const float* __restrict__ boxes,   // (B,M,4)
                 const int*   __restrict__ labels,  // (B,M)
                 const float* __restrict__ priors,  // (P,4) cxcy
                 const unsigned long long* __restrict__ pfo_key,
                 float* __restrict__ partials)      // (B*NBX, 4)
{
    const int b    = blockIdx.y;
    const int w    = threadIdx.x >> 6;
    const int lane = threadIdx.x & 63;

    __shared__ float4 sbox[MN];
    __shared__ float  sarea[MN];
    __shared__ int    slab[MN];
    __shared__ int    spfo[MN];
    __shared__ float  sred[4][4];

    if (threadIdx.x < MN) {
        float4 bx = reinterpret_cast<const float4*>(boxes)[b * MN + threadIdx.x];
        sbox[threadIdx.x]  = bx;
        sarea[threadIdx.x] = (bx.z - bx.x) * (bx.w - bx.y);
        slab[threadIdx.x]  = labels[b * MN + threadIdx.x];
        spfo[threadIdx.x]  = (int)(~(unsigned int)(pfo_key[b * MN + threadIdx.x] &
                                                   0xFFFFFFFFull));
    }
    __syncthreads();

    float conf_acc = 0.f, m_cnt = 0.f, loc_acc = 0.f, pos_cnt = 0.f; // lane0

    for (int it = 0; it < LOSS_ITERS; ++it) {
        const int p = it * (NBX * 4) + blockIdx.x * 4 + w;
        if (p >= PN) break;                     // wave-uniform; no barriers in loop

        // prior in xy form (same-address load across wave -> single fetch)
        float4 pc = reinterpret_cast<const float4*>(priors)[p];
        float hw = pc.z / 2.0f, hh = pc.w / 2.0f;
        float qx0 = pc.x - hw, qy0 = pc.y - hh;
        float qx1 = pc.x + hw, qy1 = pc.y + hh;
        float ab  = (qx1 - qx0) * (qy1 - qy0);

        // argmax IoU over the 16 objects (lanes 0..15), first-index tie-break
        unsigned long long key = 0ull;
        if (lane < MN) {
            float4 bx = sbox[lane];
            float lx = fmaxf(bx.x, qx0), ly = fmaxf(bx.y, qy0);
            float rx = fminf(bx.z, qx1), ry = fminf(bx.w, qy1);
            float inter = fmaxf(rx - lx, 0.0f) * fmaxf(ry - ly, 0.0f);
            float iou = inter / (sarea[lane] + ab - inter);
            key = ((unsigned long long)__float_as_uint(iou) << 32) |
                  (unsigned long long)(~(unsigned int)lane);
        }
        #pragma unroll
        for (int off = 1; off < 64; off <<= 1) {
            unsigned long long o = __shfl_xor(key, off, 64);
            if (o > key) key = o;
        }
        int   bestm = (int)(~(unsigned int)(key & 0xFFFFFFFFull));
        float ofp   = __uint_as_float((unsigned int)(key >> 32));

        // pfo override: obj[pfo[m]]=m (last/highest m wins), ofp[pfo[m]]=1
        bool pm = (lane < MN) && (spfo[lane] == p);
        unsigned long long mask = __ballot(pm);
        if (mask) { bestm = 63 - __clzll(mask); ofp = 1.0f; }

        bool pos = ofp >= 0.5f;
        bool neg = ofp < 0.4f;
        if (!(pos || neg)) continue;            // skip rows outside m-mask

        // coalesced score-row read: elem lane, elem 64+lane
        const float* srow = scores + ((size_t)b * PN + p) * CN;
        float r0 = srow[lane];
        float r1 = (lane < CN - 64) ? srow[64 + lane] : -INFINITY;

        float mx = fmaxf(r0, r1);
        #pragma unroll
        for (int off = 1; off < 64; off <<= 1)
            mx = fmaxf(mx, __shfl_xor(mx, off, 64));

        float es = expf(r0 - mx) + ((lane < CN - 64) ? expf(r1 - mx) : 0.0f);
        #pragma unroll
        for (int off = 1; off < 64; off <<= 1)
            es += __shfl_xor(es, off, 64);

        int lab = pos ? slab[bestm] : 0;        // wave-uniform
        float tv;
        if (lab < 64) tv = __shfl(r0, lab, 64);
        else          tv = __shfl(r1, lab - 64, 64);

        if (lane == 0) {
            float lp = tv - mx - logf(es);
            float pt = expf(lp);
            float om = 1.0f - pt;
            conf_acc += 0.25f * om * om * (-lp);
            m_cnt += 1.0f;

            if (pos) {
                float4 g = reinterpret_cast<const float4*>(plocs)[(size_t)b * PN + p];
                float cx = g.x * pc.z / 10.0f + pc.x;
                float cy = g.y * pc.w / 10.0f + pc.y;
                float ww = expf(g.z / 5.0f) * pc.z;
                float hh2 = expf(g.w / 5.0f) * pc.w;
                float px0 = cx - ww / 2.0f, py0 = cy - hh2 / 2.0f;
                float px1 = cx + ww / 2.0f, py1 = cy + hh2 / 2.0f;

                float4 gb = sbox[bestm];
                float lx = fmaxf(px0, gb.x), ly = fmaxf(py0, gb.y);
                float rx = fminf(px1, gb.z), ry = fminf(py1, gb.w);
                float inter = fmaxf(rx - lx, 0.f) * fmaxf(ry - ly, 0.f);
                float apx = (px1 - px0) * (py1 - py0);
                float agx = (gb.z - gb.x) * (gb.w - gb.y);
                float iou = inter / (apx + agx - inter + 1e-7f);
                float cpx = (px0 + px1) / 2.0f, cpy = (py0 + py1) / 2.0f;
                float cgx = (gb.x + gb.z) / 2.0f, cgy = (gb.y + gb.w) / 2.0f;
                float dx = cpx - cgx, dy = cpy - cgy;
                float d2 = dx * dx + dy * dy;
                float ex0 = fminf(px0, gb.x), ey0 = fminf(py0, gb.y);
                float ex1 = fmaxf(px1, gb.z), ey1 = fmaxf(py1, gb.w);
                float ew = ex1 - ex0, eh = ey1 - ey0;
                float c2 = ew * ew + eh * eh + 1e-7f;
                loc_acc += 1.0f - iou + d2 / c2;
                pos_cnt += 1.0f;
            }
        }
    }

    if (lane == 0) {
        sred[w][0] = conf_acc; sred[w][1] = m_cnt;
        sred[w][2] = loc_acc;  sred[w][3] = pos_cnt;
    }
    __syncthreads();
    if (threadIdx.x == 0) {
        float a = 0.f, bs = 0.f, c = 0.f, d = 0.f;
        #pragma unroll
        for (int i = 0; i < 4; ++i) {
            a += sred[i][0]; bs += sred[i][1];
            c += sred[i][2]; d += sred[i][3];
        }
        float4* po = reinterpret_cast<float4*>(partials);
        po[b * NBX + blockIdx.x] = make_float4(a, bs, c, d);
    }
}

// ---------------------------------------------------------------------------
// Kernel 3: deterministic reduction of (B*NBX) float4 partials -> scalar
// ---------------------------------------------------------------------------
__global__ __launch_bounds__(256)
void reduce_kernel(const float* __restrict__ partials, float* __restrict__ out)
{
    const int N = BN * NBX;   // 5664
    float c = 0.f, mc = 0.f, l = 0.f, pc = 0.f;
    for (int i = threadIdx.x; i < N; i += 256) {
        float4 v = reinterpret_cast<const float4*>(partials)[i];
        c += v.x; mc += v.y; l += v.z; pc += v.w;
    }
    #pragma unroll
    for (int off = 1; off < 64; off <<= 1) {
        c  += __shfl_xor(c,  off, 64);
        mc += __shfl_xor(mc, off, 64);
        l  += __shfl_xor(l,  off, 64);
        pc += __shfl_xor(pc, off, 64);
    }
    __shared__ float s[4][4];
    int lane = threadIdx.x & 63, w = threadIdx.x >> 6;
    if (lane == 0) { s[w][0] = c; s[w][1] = mc; s[w][2] = l; s[w][3] = pc; }
    __syncthreads();
    if (threadIdx.x == 0) {
        float C = 0.f, Mc = 0.f, L = 0.f, Pc = 0.f;
        #pragma unroll
        for (int i = 0; i < 4; ++i) {
            C += s[i][0]; Mc += s[i][1]; L += s[i][2]; Pc += s[i][3];
        }
        out[0] = C / fmaxf(Mc, 1.0f) + L / fmaxf(Pc, 1.0f);
    }
}

// ---------------------------------------------------------------------------
extern "C" void kernel_launch(void* const* d_in, const int* in_sizes, int n_in,
                              void* d_out, int out_size, void* d_ws, size_t ws_size,
                              hipStream_t stream)
{
    const float* plocs  = (const float*)d_in[0];  // predicted_locs  (B,P,4)
    const float* scores = (const float*)d_in[1];  // predicted_scores(B,P,C)
    const float* boxes  = (const float*)d_in[2];  // boxes           (B,M,4)
    const int*   labels = (const int*)d_in[3];    // labels          (B,M)
    const float* priors = (const float*)d_in[4];  // priors_cxcy     (P,4)
    float* out = (float*)d_out;

    char* ws = (char*)d_ws;
    unsigned long long* pfo_key = (unsigned long long*)ws;     // 512 B
    float* partials = (float*)(ws + 4096);                     // 5664*16 B

    hipMemsetAsync(pfo_key, 0, BN * MN * sizeof(unsigned long long), stream);

    dim3 gA((PN + 255) / 256, BN);
    pfo_kernel<<<gA, 256, 0, stream>>>(boxes, priors, pfo_key);

    dim3 gB(NBX, BN);
    loss_kernel<<<gB, 256, 0, stream>>>(plocs, scores, boxes, labels, priors,
                                        pfo_key, partials);
    reduce_kernel<<<1, 256, 0, stream>>>(partials, out);
}

// Round 3
// 379.542 us; speedup vs baseline: 1.4170x; 1.4170x over previous
//
#include <hip/hip_runtime.h>
#include <math.h>

#define PN 22536
#define BN 32
#define MN 16
#define CN 81
#define NMB ((PN + 255) / 256)   // 89 match blocks per image
#define NCB 2048                 // conf-kernel blocks

// ---------------------------------------------------------------------------
// Kernel 1: per-object best-prior argmax (prior_for_each_object).
// Packed key (iou_bits<<32 | ~p): max => first-occurrence argmax over p.
// ---------------------------------------------------------------------------
__global__ __launch_bounds__(256)
void pfo_kernel(const float* __restrict__ boxes,    // (B,M,4) xyxy
                const float* __restrict__ priors,   // (P,4) cxcy
                unsigned long long* __restrict__ pfo_key) // (B,M)
{
    const int b = blockIdx.y;
    const int p = blockIdx.x * 256 + threadIdx.x;

    __shared__ float4 sbox[MN];
    __shared__ float  sarea[MN];
    __shared__ unsigned long long skey[MN];
    if (threadIdx.x < MN) {
        float4 bx = reinterpret_cast<const float4*>(boxes)[b * MN + threadIdx.x];
        sbox[threadIdx.x]  = bx;
        sarea[threadIdx.x] = (bx.z - bx.x) * (bx.w - bx.y);
        skey[threadIdx.x]  = 0ull;
    }
    __syncthreads();

    float x0 = 0.f, y0 = 0.f, x1 = 0.f, y1 = 0.f, ab = 0.f;
    const bool valid = (p < PN);
    if (valid) {
        float4 pc = reinterpret_cast<const float4*>(priors)[p];
        float hw = pc.z / 2.0f, hh = pc.w / 2.0f;
        x0 = pc.x - hw; y0 = pc.y - hh;
        x1 = pc.x + hw; y1 = pc.y + hh;
        ab = (x1 - x0) * (y1 - y0);
    }

    const int lane = threadIdx.x & 63;
    #pragma unroll
    for (int m = 0; m < MN; ++m) {
        unsigned long long key = 0ull;
        if (valid) {
            float4 bx = sbox[m];
            float lx = fmaxf(bx.x, x0), ly = fmaxf(bx.y, y0);
            float rx = fminf(bx.z, x1), ry = fminf(bx.w, y1);
            float inter = fmaxf(rx - lx, 0.0f) * fmaxf(ry - ly, 0.0f);
            float iou = inter / (sarea[m] + ab - inter);
            key = ((unsigned long long)__float_as_uint(iou) << 32) |
                  (unsigned long long)(~(unsigned int)p);
        }
        #pragma unroll
        for (int off = 32; off >= 1; off >>= 1) {
            unsigned long long o = __shfl_down(key, (unsigned)off, 64);
            if (o > key) key = o;
        }
        if (lane == 0) atomicMax(&skey[m], key);
    }
    __syncthreads();
    if (threadIdx.x < MN)
        atomicMax(&pfo_key[b * MN + threadIdx.x], skey[threadIdx.x]);
}

// ---------------------------------------------------------------------------
// Kernel 2: thread-per-prior matching + DIoU + counts. Emits one byte/row:
// target label for focal loss (0..80) or 255 = skip (0.4 <= ofp < 0.5 band).
// Accumulates (loc_sum, pos_cnt, m_cnt) per block.
// ---------------------------------------------------------------------------
__global__ __launch_bounds__(256)
void match_kernel(const float* __restrict__ boxes,   // (B,M,4)
                  const int*   __restrict__ labels,  // (B,M)
                  const float* __restrict__ priors,  // (P,4) cxcy
                  const float* __restrict__ plocs,   // (B,P,4)
                  const unsigned long long* __restrict__ pfo_key,
                  unsigned char* __restrict__ labbyte,  // (B*P)
                  float4* __restrict__ mpart)           // (B*NMB)
{
    const int b = blockIdx.y;
    const int p = blockIdx.x * 256 + threadIdx.x;

    __shared__ float4 sbox[MN];
    __shared__ float  sarea[MN];
    __shared__ int    slab[MN];
    __shared__ int    spfo[MN];
    __shared__ float  sred[4][3];

    if (threadIdx.x < MN) {
        float4 bx = reinterpret_cast<const float4*>(boxes)[b * MN + threadIdx.x];
        sbox[threadIdx.x]  = bx;
        sarea[threadIdx.x] = (bx.z - bx.x) * (bx.w - bx.y);
        slab[threadIdx.x]  = labels[b * MN + threadIdx.x];
        spfo[threadIdx.x]  = (int)(~(unsigned int)(pfo_key[b * MN + threadIdx.x] &
                                                   0xFFFFFFFFull));
    }
    __syncthreads();

    float loc = 0.f, mc = 0.f, psc = 0.f;
    if (p < PN) {
        float4 pc = reinterpret_cast<const float4*>(priors)[p];
        float hw = pc.z / 2.0f, hh = pc.w / 2.0f;
        float qx0 = pc.x - hw, qy0 = pc.y - hh;
        float qx1 = pc.x + hw, qy1 = pc.y + hh;
        float ab  = (qx1 - qx0) * (qy1 - qy0);

        float best = -1.0f;
        int bestm = 0;
        #pragma unroll
        for (int m = 0; m < MN; ++m) {
            float4 bx = sbox[m];
            float lx = fmaxf(bx.x, qx0), ly = fmaxf(bx.y, qy0);
            float rx = fminf(bx.z, qx1), ry = fminf(bx.w, qy1);
            float inter = fmaxf(rx - lx, 0.0f) * fmaxf(ry - ly, 0.0f);
            float iou = inter / (sarea[m] + ab - inter);
            if (iou > best) { best = iou; bestm = m; }   // first-index wins
        }
        // pfo override: ascending m => last m wins for duplicate priors
        #pragma unroll
        for (int m = 0; m < MN; ++m)
            if (spfo[m] == p) { bestm = m; best = 1.0f; }

        bool pos = best >= 0.5f;
        bool neg = best < 0.4f;
        labbyte[(size_t)b * PN + p] =
            pos ? (unsigned char)slab[bestm] : (neg ? (unsigned char)0
                                                    : (unsigned char)255);
        if (pos || neg) mc = 1.0f;

        if (pos) {
            float4 g = reinterpret_cast<const float4*>(plocs)[(size_t)b * PN + p];
            float cx = g.x * pc.z / 10.0f + pc.x;
            float cy = g.y * pc.w / 10.0f + pc.y;
            float ww = expf(g.z / 5.0f) * pc.z;
            float hh2 = expf(g.w / 5.0f) * pc.w;
            float px0 = cx - ww / 2.0f, py0 = cy - hh2 / 2.0f;
            float px1 = cx + ww / 2.0f, py1 = cy + hh2 / 2.0f;

            float4 gb = sbox[bestm];
            float lx = fmaxf(px0, gb.x), ly = fmaxf(py0, gb.y);
            float rx = fminf(px1, gb.z), ry = fminf(py1, gb.w);
            float inter = fmaxf(rx - lx, 0.f) * fmaxf(ry - ly, 0.f);
            float apx = (px1 - px0) * (py1 - py0);
            float agx = (gb.z - gb.x) * (gb.w - gb.y);
            float iou = inter / (apx + agx - inter + 1e-7f);
            float cpx = (px0 + px1) / 2.0f, cpy = (py0 + py1) / 2.0f;
            float cgx = (gb.x + gb.z) / 2.0f, cgy = (gb.y + gb.w) / 2.0f;
            float dx = cpx - cgx, dy = cpy - cgy;
            float d2 = dx * dx + dy * dy;
            float ex0 = fminf(px0, gb.x), ey0 = fminf(py0, gb.y);
            float ex1 = fmaxf(px1, gb.z), ey1 = fmaxf(py1, gb.w);
            float ew = ex1 - ex0, eh = ey1 - ey0;
            float c2 = ew * ew + eh * eh + 1e-7f;
            loc = 1.0f - iou + d2 / c2;
            psc = 1.0f;
        }
    }

    #pragma unroll
    for (int off = 32; off >= 1; off >>= 1) {
        loc += __shfl_down(loc, (unsigned)off, 64);
        mc  += __shfl_down(mc,  (unsigned)off, 64);
        psc += __shfl_down(psc, (unsigned)off, 64);
    }
    const int lane = threadIdx.x & 63;
    const int w = threadIdx.x >> 6;
    if (lane == 0) { sred[w][0] = loc; sred[w][1] = mc; sred[w][2] = psc; }
    __syncthreads();
    if (threadIdx.x == 0) {
        float a = 0.f, bsum = 0.f, c = 0.f;
        #pragma unroll
        for (int i = 0; i < 4; ++i) {
            a += sred[i][0]; bsum += sred[i][1]; c += sred[i][2];
        }
        mpart[b * NMB + blockIdx.x] = make_float4(a, c, bsum, 0.f);
    }
}

// ---------------------------------------------------------------------------
// Kernel 3: focal confidence loss. 16 lanes per row, 4 rows per wave.
// Lane j holds elements {j, j+16, j+32, j+48, j+64} (+ elem 80 on j==0);
// 4-step group shfl_xor reductions for max and sum-exp.
// ---------------------------------------------------------------------------
__global__ __launch_bounds__(256)
void conf_kernel(const float* __restrict__ scores,       // (B,P,C)
                 const unsigned char* __restrict__ labbyte,
                 float* __restrict__ cpart)              // (gridDim.x)
{
    const int lane = threadIdx.x & 63;
    const int j    = lane & 15;
    const int g    = (lane >> 4);
    const int wave_g = (blockIdx.x * 256 + threadIdx.x) >> 6;
    const int stride = NCB * 16;     // rows per grid iteration
    const int R = BN * PN;

    float conf = 0.f;

    for (int row = wave_g * 4 + g; row < R; row += stride) {
        int lb = labbyte[row];                 // group-uniform (HW broadcast)
        if (lb == 255) continue;               // 0.4<=ofp<0.5 band: skip

        const float* srow = scores + (size_t)row * CN;
        float v0 = srow[j];
        float v1 = srow[j + 16];
        float v2 = srow[j + 32];
        float v3 = srow[j + 48];
        float v4 = srow[j + 64];
        float v5 = (j == 0) ? srow[80] : -INFINITY;

        float mx = fmaxf(fmaxf(fmaxf(v0, v1), fmaxf(v2, v3)), fmaxf(v4, v5));
        #pragma unroll
        for (int off = 1; off < 16; off <<= 1)
            mx = fmaxf(mx, __shfl_xor(mx, off, 64));

        float es = expf(v0 - mx) + expf(v1 - mx) + expf(v2 - mx) +
                   expf(v3 - mx) + expf(v4 - mx) + expf(v5 - mx);
        #pragma unroll
        for (int off = 1; off < 16; off <<= 1)
            es += __shfl_xor(es, off, 64);

        // fetch target logit: element lb lives in lane (lb&15), slot (lb>>4)
        int hi = lb >> 4, lo = lb & 15;
        float sel = v0;
        sel = (hi == 1) ? v1 : sel;
        sel = (hi == 2) ? v2 : sel;
        sel = (hi == 3) ? v3 : sel;
        sel = (hi == 4) ? v4 : sel;
        sel = (hi == 5) ? v5 : sel;
        float tv = __shfl(sel, (lane & 48) | lo, 64);

        float lp = tv - mx - logf(es);
        float pt = expf(lp);
        float om = 1.0f - pt;
        if (j == 0) conf += 0.25f * om * om * (-lp);
    }

    #pragma unroll
    for (int off = 1; off < 64; off <<= 1)
        conf += __shfl_xor(conf, off, 64);

    __shared__ float sred[4];
    if (lane == 0) sred[threadIdx.x >> 6] = conf;
    __syncthreads();
    if (threadIdx.x == 0)
        cpart[blockIdx.x] = sred[0] + sred[1] + sred[2] + sred[3];
}

// ---------------------------------------------------------------------------
// Kernel 4: deterministic final reduction -> scalar loss
// ---------------------------------------------------------------------------
__global__ __launch_bounds__(256)
void reduce_kernel(const float4* __restrict__ mpart,   // (B*NMB): loc,pos,mcnt
                   const float*  __restrict__ cpart,   // (NCB)
                   float* __restrict__ out)
{
    const int NM = BN * NMB;
    float loc = 0.f, pcnt = 0.f, mcnt = 0.f, conf = 0.f;
    for (int i = threadIdx.x; i < NM; i += 256) {
        float4 v = mpart[i];
        loc += v.x; pcnt += v.y; mcnt += v.z;
    }
    for (int i = threadIdx.x; i < NCB; i += 256)
        conf += cpart[i];

    #pragma unroll
    for (int off = 1; off < 64; off <<= 1) {
        loc  += __shfl_xor(loc,  off, 64);
        pcnt += __shfl_xor(pcnt, off, 64);
        mcnt += __shfl_xor(mcnt, off, 64);
        conf += __shfl_xor(conf, off, 64);
    }
    __shared__ float s[4][4];
    int lane = threadIdx.x & 63, w = threadIdx.x >> 6;
    if (lane == 0) { s[w][0] = loc; s[w][1] = pcnt; s[w][2] = mcnt; s[w][3] = conf; }
    __syncthreads();
    if (threadIdx.x == 0) {
        float L = 0.f, Pc = 0.f, Mc = 0.f, Cf = 0.f;
        #pragma unroll
        for (int i = 0; i < 4; ++i) {
            L += s[i][0]; Pc += s[i][1]; Mc += s[i][2]; Cf += s[i][3];
        }
        out[0] = Cf / fmaxf(Mc, 1.0f) + L / fmaxf(Pc, 1.0f);
    }
}

// ---------------------------------------------------------------------------
extern "C" void kernel_launch(void* const* d_in, const int* in_sizes, int n_in,
                              void* d_out, int out_size, void* d_ws, size_t ws_size,
                              hipStream_t stream)
{
    const float* plocs  = (const float*)d_in[0];  // predicted_locs  (B,P,4)
    const float* scores = (const float*)d_in[1];  // predicted_scores(B,P,C)
    const float* boxes  = (const float*)d_in[2];  // boxes           (B,M,4)
    const int*   labels = (const int*)d_in[3];    // labels          (B,M)
    const float* priors = (const float*)d_in[4];  // priors_cxcy     (P,4)
    float* out = (float*)d_out;

    char* ws = (char*)d_ws;
    unsigned long long* pfo_key = (unsigned long long*)ws;        // 4096 B
    unsigned char* labbyte = (unsigned char*)(ws + 4096);         // B*P = 721152
    float4* mpart = (float4*)(ws + 4096 + 721152);                // 2848*16 B
    float*  cpart = (float*)(ws + 4096 + 721152 + BN * NMB * 16); // NCB*4 B

    hipMemsetAsync(pfo_key, 0, BN * MN * sizeof(unsigned long long), stream);

    dim3 gA(NMB, BN);
    pfo_kernel<<<gA, 256, 0, stream>>>(boxes, priors, pfo_key);
    match_kernel<<<gA, 256, 0, stream>>>(boxes, labels, priors, plocs,
                                         pfo_key, labbyte, mpart);
    conf_kernel<<<NCB, 256, 0, stream>>>(scores, labbyte, cpart);
    reduce_kernel<<<1, 256, 0, stream>>>(mpart, cpart, out);
}